// Round 2
// baseline (194.211 us; speedup 1.0000x reference)
//
#include <hip/hip_runtime.h>

#define MDIM 2048
#define NDIM 4096
#define KDIM 4096

typedef __bf16 bf16x8 __attribute__((ext_vector_type(8)));
typedef float f32x4 __attribute__((ext_vector_type(4)));

// CK-style addrspace cast idiom (flat LDS addr low 32 bits == LDS offset on gfx9+)
__device__ inline void load_lds16(const void* gptr, void* lptr) {
    auto g1 = reinterpret_cast<const __attribute__((address_space(1))) unsigned int*>(
        reinterpret_cast<uintptr_t>(gptr));
    auto l3 = reinterpret_cast<__attribute__((address_space(3))) unsigned int*>(
        reinterpret_cast<uintptr_t>(lptr));
    __builtin_amdgcn_global_load_lds(g1, l3, 16, 0, 0);
}

// ---------------------------------------------------------------------------
// Kernel 1: BCQ dequant -> W^T bf16 [N, K]
// v2 mapping: k32 = id & 127, n = id >> 7. Lanes within a wave cover
// consecutive k32 for one n -> each lane writes 64B contiguous, and the wave
// writes 4KB fully contiguous along K (full-line coalesced stores).
// Reads become lane-strided 4B (16KB apart) but binary is 8MB and adjacent-n
// blocks are concurrent -> L2 absorbs the re-reads.
// ---------------------------------------------------------------------------
__global__ __launch_bounds__(256) void dequant_kernel(
    const int* __restrict__ binary,   // [K/32, 4, N]
    const float* __restrict__ alpha,  // [K/128, 4, N]
    const float* __restrict__ q_bias, // [K/128, N]
    __bf16* __restrict__ WT)          // [N, K]
{
    const int id = blockIdx.x * 256 + threadIdx.x;   // N * K/32 = 524288 threads
    const int k32 = id & 127;        // 0..127 (fastest within wave)
    const int n = id >> 7;
    const int g = k32 >> 2;          // group = (k32*32)/128

    const unsigned w0 = (unsigned)binary[(k32 * 4 + 0) * NDIM + n];
    const unsigned w1 = (unsigned)binary[(k32 * 4 + 1) * NDIM + n];
    const unsigned w2 = (unsigned)binary[(k32 * 4 + 2) * NDIM + n];
    const unsigned w3 = (unsigned)binary[(k32 * 4 + 3) * NDIM + n];
    const float a0 = alpha[(g * 4 + 0) * NDIM + n];
    const float a1 = alpha[(g * 4 + 1) * NDIM + n];
    const float a2 = alpha[(g * 4 + 2) * NDIM + n];
    const float a3 = alpha[(g * 4 + 3) * NDIM + n];
    const float qb = q_bias[g * NDIM + n];

    union { __bf16 h[32]; uint4 q[4]; } u;
#pragma unroll
    for (int i = 0; i < 32; ++i) {
        float v = qb;
        v += ((w0 >> i) & 1u) ? a0 : -a0;
        v += ((w1 >> i) & 1u) ? a1 : -a1;
        v += ((w2 >> i) & 1u) ? a2 : -a2;
        v += ((w3 >> i) & 1u) ? a3 : -a3;
        u.h[i] = (__bf16)v;
    }
    uint4* dst = reinterpret_cast<uint4*>(WT + (size_t)n * KDIM + k32 * 32);
#pragma unroll
    for (int j = 0; j < 4; ++j) dst[j] = u.q[j];
}

// ---------------------------------------------------------------------------
// Kernel 2: x fp32 -> bf16 [M, K]
// ---------------------------------------------------------------------------
__global__ __launch_bounds__(256) void castx_kernel(
    const float* __restrict__ x, __bf16* __restrict__ xb)
{
    const int id = blockIdx.x * 256 + threadIdx.x;   // M*K/8 = 1048576 threads
    const float4* xv = reinterpret_cast<const float4*>(x) + (size_t)id * 2;
    const float4 v0 = xv[0];
    const float4 v1 = xv[1];
    union { __bf16 h[8]; uint4 q; } u;
    u.h[0] = (__bf16)v0.x; u.h[1] = (__bf16)v0.y;
    u.h[2] = (__bf16)v0.z; u.h[3] = (__bf16)v0.w;
    u.h[4] = (__bf16)v1.x; u.h[5] = (__bf16)v1.y;
    u.h[6] = (__bf16)v1.z; u.h[7] = (__bf16)v1.w;
    reinterpret_cast<uint4*>(xb)[id] = u.q;
}

// ---------------------------------------------------------------------------
// Kernel 3: C[M,N] = A[M,K](bf16) * WT[N,K]^T(bf16) + bias, fp32 out.
// 128x128 block tile, BK=64, 256 threads = 4 waves in 2x2 of 64x64.
// global_load_lds width=16 staging; XOR granule swizzle on the GLOBAL source
// address (LDS dest must be lane-contiguous) for conflict-free ds_read_b128.
// ---------------------------------------------------------------------------
__global__ __launch_bounds__(256) void gemm_kernel(
    const __bf16* __restrict__ A,   // [M, K]
    const __bf16* __restrict__ BT,  // [N, K]
    const float* __restrict__ bias, // [N]
    float* __restrict__ C)          // [M, N]
{
    constexpr int BM = 128, BN = 128, BK = 64;
    __shared__ __align__(16) __bf16 As[BM * BK];
    __shared__ __align__(16) __bf16 Bs[BN * BK];

    const int t = threadIdx.x;
    const int lane = t & 63;
    const int wave = t >> 6;
    const int wm = (wave >> 1) << 6;   // 0 or 64
    const int wn = (wave & 1) << 6;
    const int bm = blockIdx.x * BM;
    const int bn = blockIdx.y * BN;

    // Staging: tile = 1024 granules of 16B; thread stages granule s = r*256+t.
    // LDS slot s holds global granule g = (s&7) ^ (row&7) of row m = s>>3.
    int a_goff[4], b_goff[4], lds_slot[4];
#pragma unroll
    for (int r = 0; r < 4; ++r) {
        const int s = r * 256 + t;
        const int m = s >> 3;
        const int g = (s & 7) ^ (m & 7);
        lds_slot[r] = s;
        a_goff[r] = (bm + m) * KDIM + g * 8;
        b_goff[r] = (bn + m) * KDIM + g * 8;
    }

    // MFMA fragment read addressing (granule units)
    const int r16 = lane & 15;
    const int kq = lane >> 4;          // quad: k-offset quad*8
    const int rA = wm + r16;
    const int rB = wn + r16;
    const int aBase = rA * 8, aX = rA & 7;
    const int bBase = rB * 8, bX = rB & 7;

    const bf16x8* Av = reinterpret_cast<const bf16x8*>(As);
    const bf16x8* Bv = reinterpret_cast<const bf16x8*>(Bs);

    f32x4 acc[4][4];
#pragma unroll
    for (int i = 0; i < 4; ++i)
#pragma unroll
        for (int j = 0; j < 4; ++j)
            acc[i][j] = f32x4{0.f, 0.f, 0.f, 0.f};

    for (int kt = 0; kt < KDIM; kt += BK) {
        __syncthreads();               // prior ds_reads done before overwrite
#pragma unroll
        for (int r = 0; r < 4; ++r) {
            load_lds16(A + a_goff[r] + kt, As + lds_slot[r] * 8);
            load_lds16(BT + b_goff[r] + kt, Bs + lds_slot[r] * 8);
        }
        __syncthreads();               // compiler drains vmcnt before barrier

#pragma unroll
        for (int ks = 0; ks < 2; ++ks) {
            bf16x8 af[4], bf[4];
#pragma unroll
            for (int mi = 0; mi < 4; ++mi)
                af[mi] = Av[aBase + mi * 128 + ((ks * 4 + kq) ^ aX)];
#pragma unroll
            for (int ni = 0; ni < 4; ++ni)
                bf[ni] = Bv[bBase + ni * 128 + ((ks * 4 + kq) ^ bX)];
#pragma unroll
            for (int mi = 0; mi < 4; ++mi)
#pragma unroll
                for (int ni = 0; ni < 4; ++ni)
                    acc[mi][ni] = __builtin_amdgcn_mfma_f32_16x16x32_bf16(
                        af[mi], bf[ni], acc[mi][ni], 0, 0, 0);
        }
    }

    // Epilogue: C col = lane&15, row = quad*4 + reg  (verified m89/m91 map)
    float bv[4];
#pragma unroll
    for (int ni = 0; ni < 4; ++ni)
        bv[ni] = bias[bn + wn + ni * 16 + r16];

    const int row0 = bm + wm + kq * 4;
#pragma unroll
    for (int mi = 0; mi < 4; ++mi) {
#pragma unroll
        for (int rr = 0; rr < 4; ++rr) {
            const int row = row0 + mi * 16 + rr;
            float* crow = C + (size_t)row * NDIM + bn + wn + r16;
#pragma unroll
            for (int ni = 0; ni < 4; ++ni)
                crow[ni * 16] = acc[mi][ni][rr] + bv[ni];
        }
    }
}

extern "C" void kernel_launch(void* const* d_in, const int* in_sizes, int n_in,
                              void* d_out, int out_size, void* d_ws, size_t ws_size,
                              hipStream_t stream) {
    const float* x      = (const float*)d_in[0];   // [1, 2048, 4096]
    const int*   binary = (const int*)d_in[1];     // [128, 4, 4096]
    const float* alpha  = (const float*)d_in[2];   // [32, 4, 4096]
    const float* q_bias = (const float*)d_in[3];   // [32, 4096]
    const float* bias   = (const float*)d_in[4];   // [4096]
    float* out = (float*)d_out;                    // [1, 2048, 4096] fp32

    __bf16* WT = (__bf16*)d_ws;                        // 32 MB
    __bf16* Xb = WT + (size_t)NDIM * KDIM;             // 16 MB

    dequant_kernel<<<(NDIM * (KDIM / 32)) / 256, 256, 0, stream>>>(binary, alpha, q_bias, WT);
    castx_kernel<<<(MDIM * KDIM / 8) / 256, 256, 0, stream>>>(x, Xb);

    dim3 grid(MDIM / 128, NDIM / 128);
    gemm_kernel<<<grid, 256, 0, stream>>>(Xb, WT, bias, out);
}

// Round 3
// 181.668 us; speedup vs baseline: 1.0690x; 1.0690x over previous
//
#include <hip/hip_runtime.h>

#define MDIM 2048
#define NDIM 4096
#define KDIM 4096

typedef __bf16 bf16x8 __attribute__((ext_vector_type(8)));
typedef float f32x4 __attribute__((ext_vector_type(4)));

// CK-style addrspace cast idiom (flat LDS addr low 32 bits == LDS offset on gfx9+)
__device__ inline void load_lds16(const void* gptr, void* lptr) {
    auto g1 = reinterpret_cast<const __attribute__((address_space(1))) unsigned int*>(
        reinterpret_cast<uintptr_t>(gptr));
    auto l3 = reinterpret_cast<__attribute__((address_space(3))) unsigned int*>(
        reinterpret_cast<uintptr_t>(lptr));
    __builtin_amdgcn_global_load_lds(g1, l3, 16, 0, 0);
}

// ---------------------------------------------------------------------------
// Kernel 1 (v3): BCQ dequant -> W^T bf16 [N, K], LDS-transposed.
// Block tile: 64 n  x  8 k32-words (256 k). Grid = (4096/64, 128/8) = 64x16.
// Phase 1: lane -> n (binary/alpha reads are 64x4B = 2 full lines / load).
//   Each thread computes 2 cells of 32 weights, packs bf16x2 in registers,
//   stores uint4 granules into LDS rows padded to 33 granules (528 B) --
//   (33n+g)*4 mod 32 spreads 64 lanes over 8 bank-quads = b128 BW floor.
// Phase 2: lane -> k granule; each wave writes 2 rows x 512B contiguous
//   (full 128B lines) to WT.
// ---------------------------------------------------------------------------
__global__ __launch_bounds__(256) void dequant_kernel(
    const int* __restrict__ binary,   // [K/32, 4, N]
    const float* __restrict__ alpha,  // [K/128, 4, N]
    const float* __restrict__ q_bias, // [K/128, N]
    __bf16* __restrict__ WT)          // [N, K]
{
    __shared__ __align__(16) unsigned Ls[64 * 132];   // 64 rows x 33 granules

    const int t = threadIdx.x;
    const int n0 = blockIdx.x * 64;
    const int k32_0 = blockIdx.y * 8;
    const int n_l = t & 63;            // lane -> n  (coalesced global reads)
    const int k_l = t >> 6;            // wave id: 0..3
    const int n = n0 + n_l;

    uint4* L4 = reinterpret_cast<uint4*>(Ls);

#pragma unroll
    for (int c = 0; c < 2; ++c) {
        const int k32 = k32_0 + k_l * 2 + c;
        const int g = k32 >> 2;

        const unsigned w0 = (unsigned)binary[(k32 * 4 + 0) * NDIM + n];
        const unsigned w1 = (unsigned)binary[(k32 * 4 + 1) * NDIM + n];
        const unsigned w2 = (unsigned)binary[(k32 * 4 + 2) * NDIM + n];
        const unsigned w3 = (unsigned)binary[(k32 * 4 + 3) * NDIM + n];
        const float a0 = alpha[(g * 4 + 0) * NDIM + n];
        const float a1 = alpha[(g * 4 + 1) * NDIM + n];
        const float a2 = alpha[(g * 4 + 2) * NDIM + n];
        const float a3 = alpha[(g * 4 + 3) * NDIM + n];
        const float qb = q_bias[g * NDIM + n];

        const int cellg = (k_l * 2 + c) * 4;          // granule base in row
#pragma unroll
        for (int j = 0; j < 4; ++j) {                  // granule = 8 weights
            unsigned pk[4];
#pragma unroll
            for (int h = 0; h < 4; ++h) {              // pair of weights
                const int i0 = j * 8 + h * 2;
                float v0 = qb, v1 = qb;
                v0 += ((w0 >> i0) & 1u) ? a0 : -a0;
                v0 += ((w1 >> i0) & 1u) ? a1 : -a1;
                v0 += ((w2 >> i0) & 1u) ? a2 : -a2;
                v0 += ((w3 >> i0) & 1u) ? a3 : -a3;
                const int i1 = i0 + 1;
                v1 += ((w0 >> i1) & 1u) ? a0 : -a0;
                v1 += ((w1 >> i1) & 1u) ? a1 : -a1;
                v1 += ((w2 >> i1) & 1u) ? a2 : -a2;
                v1 += ((w3 >> i1) & 1u) ? a3 : -a3;
                const unsigned lo = __builtin_bit_cast(unsigned short, (__bf16)v0);
                const unsigned hi = __builtin_bit_cast(unsigned short, (__bf16)v1);
                pk[h] = lo | (hi << 16);
            }
            uint4 q;
            q.x = pk[0]; q.y = pk[1]; q.z = pk[2]; q.w = pk[3];
            L4[n_l * 33 + cellg + j] = q;
        }
    }

    __syncthreads();

    // Phase 2: stream out. 64 rows x 32 granules = 2048 granules, 8 passes.
    uint4* dstv = reinterpret_cast<uint4*>(WT);
    const int kcol0 = blockIdx.y * 32;                // uint4 column base
#pragma unroll
    for (int p = 0; p < 8; ++p) {
        const int idx = p * 256 + t;
        const int row = idx >> 5;
        const int gI = idx & 31;
        const uint4 q = L4[row * 33 + gI];
        dstv[(size_t)(n0 + row) * (KDIM / 8) + kcol0 + gI] = q;
    }
}

// ---------------------------------------------------------------------------
// Kernel 2: x fp32 -> bf16 [M, K]
// ---------------------------------------------------------------------------
__global__ __launch_bounds__(256) void castx_kernel(
    const float* __restrict__ x, __bf16* __restrict__ xb)
{
    const int id = blockIdx.x * 256 + threadIdx.x;   // M*K/8 = 1048576 threads
    const float4* xv = reinterpret_cast<const float4*>(x) + (size_t)id * 2;
    const float4 v0 = xv[0];
    const float4 v1 = xv[1];
    union { __bf16 h[8]; uint4 q; } u;
    u.h[0] = (__bf16)v0.x; u.h[1] = (__bf16)v0.y;
    u.h[2] = (__bf16)v0.z; u.h[3] = (__bf16)v0.w;
    u.h[4] = (__bf16)v1.x; u.h[5] = (__bf16)v1.y;
    u.h[6] = (__bf16)v1.z; u.h[7] = (__bf16)v1.w;
    reinterpret_cast<uint4*>(xb)[id] = u.q;
}

// ---------------------------------------------------------------------------
// Kernel 3: C[M,N] = A[M,K](bf16) * WT[N,K]^T(bf16) + bias, fp32 out.
// (unchanged from round 1: 128x128 tile, BK=64, XOR-swizzled global_load_lds)
// ---------------------------------------------------------------------------
__global__ __launch_bounds__(256) void gemm_kernel(
    const __bf16* __restrict__ A,   // [M, K]
    const __bf16* __restrict__ BT,  // [N, K]
    const float* __restrict__ bias, // [N]
    float* __restrict__ C)          // [M, N]
{
    constexpr int BM = 128, BN = 128, BK = 64;
    __shared__ __align__(16) __bf16 As[BM * BK];
    __shared__ __align__(16) __bf16 Bs[BN * BK];

    const int t = threadIdx.x;
    const int lane = t & 63;
    const int wave = t >> 6;
    const int wm = (wave >> 1) << 6;   // 0 or 64
    const int wn = (wave & 1) << 6;
    const int bm = blockIdx.x * BM;
    const int bn = blockIdx.y * BN;

    int a_goff[4], b_goff[4], lds_slot[4];
#pragma unroll
    for (int r = 0; r < 4; ++r) {
        const int s = r * 256 + t;
        const int m = s >> 3;
        const int g = (s & 7) ^ (m & 7);
        lds_slot[r] = s;
        a_goff[r] = (bm + m) * KDIM + g * 8;
        b_goff[r] = (bn + m) * KDIM + g * 8;
    }

    const int r16 = lane & 15;
    const int kq = lane >> 4;
    const int rA = wm + r16;
    const int rB = wn + r16;
    const int aBase = rA * 8, aX = rA & 7;
    const int bBase = rB * 8, bX = rB & 7;

    const bf16x8* Av = reinterpret_cast<const bf16x8*>(As);
    const bf16x8* Bv = reinterpret_cast<const bf16x8*>(Bs);

    f32x4 acc[4][4];
#pragma unroll
    for (int i = 0; i < 4; ++i)
#pragma unroll
        for (int j = 0; j < 4; ++j)
            acc[i][j] = f32x4{0.f, 0.f, 0.f, 0.f};

    for (int kt = 0; kt < KDIM; kt += BK) {
        __syncthreads();
#pragma unroll
        for (int r = 0; r < 4; ++r) {
            load_lds16(A + a_goff[r] + kt, As + lds_slot[r] * 8);
            load_lds16(BT + b_goff[r] + kt, Bs + lds_slot[r] * 8);
        }
        __syncthreads();

#pragma unroll
        for (int ks = 0; ks < 2; ++ks) {
            bf16x8 af[4], bf[4];
#pragma unroll
            for (int mi = 0; mi < 4; ++mi)
                af[mi] = Av[aBase + mi * 128 + ((ks * 4 + kq) ^ aX)];
#pragma unroll
            for (int ni = 0; ni < 4; ++ni)
                bf[ni] = Bv[bBase + ni * 128 + ((ks * 4 + kq) ^ bX)];
#pragma unroll
            for (int mi = 0; mi < 4; ++mi)
#pragma unroll
                for (int ni = 0; ni < 4; ++ni)
                    acc[mi][ni] = __builtin_amdgcn_mfma_f32_16x16x32_bf16(
                        af[mi], bf[ni], acc[mi][ni], 0, 0, 0);
        }
    }

    float bv[4];
#pragma unroll
    for (int ni = 0; ni < 4; ++ni)
        bv[ni] = bias[bn + wn + ni * 16 + r16];

    const int row0 = bm + wm + kq * 4;
#pragma unroll
    for (int mi = 0; mi < 4; ++mi) {
#pragma unroll
        for (int rr = 0; rr < 4; ++rr) {
            const int row = row0 + mi * 16 + rr;
            float* crow = C + (size_t)row * NDIM + bn + wn + r16;
#pragma unroll
            for (int ni = 0; ni < 4; ++ni)
                crow[ni * 16] = acc[mi][ni][rr] + bv[ni];
        }
    }
}

extern "C" void kernel_launch(void* const* d_in, const int* in_sizes, int n_in,
                              void* d_out, int out_size, void* d_ws, size_t ws_size,
                              hipStream_t stream) {
    const float* x      = (const float*)d_in[0];   // [1, 2048, 4096]
    const int*   binary = (const int*)d_in[1];     // [128, 4, 4096]
    const float* alpha  = (const float*)d_in[2];   // [32, 4, 4096]
    const float* q_bias = (const float*)d_in[3];   // [32, 4096]
    const float* bias   = (const float*)d_in[4];   // [4096]
    float* out = (float*)d_out;                    // [1, 2048, 4096] fp32

    __bf16* WT = (__bf16*)d_ws;                        // 32 MB
    __bf16* Xb = WT + (size_t)NDIM * KDIM;             // 16 MB

    dim3 dq_grid(NDIM / 64, KDIM / 32 / 8);            // 64 x 16
    dequant_kernel<<<dq_grid, 256, 0, stream>>>(binary, alpha, q_bias, WT);
    castx_kernel<<<(MDIM * KDIM / 8) / 256, 256, 0, stream>>>(x, Xb);

    dim3 grid(MDIM / 128, NDIM / 128);
    gemm_kernel<<<grid, 256, 0, stream>>>(Xb, WT, bias, out);
}

// Round 5
// 179.982 us; speedup vs baseline: 1.0791x; 1.0094x over previous
//
#include <hip/hip_runtime.h>

#define MDIM 2048
#define NDIM 4096
#define KDIM 4096

typedef __bf16 bf16x8 __attribute__((ext_vector_type(8)));
typedef float f32x4 __attribute__((ext_vector_type(4)));

// CK-style addrspace cast idiom (flat LDS addr low 32 bits == LDS offset on gfx9+)
__device__ inline void load_lds16(const void* gptr, void* lptr) {
    auto g1 = reinterpret_cast<const __attribute__((address_space(1))) unsigned int*>(
        reinterpret_cast<uintptr_t>(gptr));
    auto l3 = reinterpret_cast<__attribute__((address_space(3))) unsigned int*>(
        reinterpret_cast<uintptr_t>(lptr));
    __builtin_amdgcn_global_load_lds(g1, l3, 16, 0, 0);
}

// ---------------------------------------------------------------------------
// Prologue (one dispatch, 1536 blocks):
//   blocks 0..1023  : BCQ dequant -> WT bf16 [N,K]  (v3 LDS-transpose tile:
//                     64 n x 8 k32-words; both global sides full-line coalesced)
//   blocks 1024..1535: x fp32 -> bf16 Xb [M,K] (8 uint4 units/thread)
// Merged to drop one dispatch (R1-R3 showed a ~73us residual invariant to
// prologue memory-pattern rewrites -> testing per-dispatch overhead).
// ---------------------------------------------------------------------------
__global__ __launch_bounds__(256) void prologue_kernel(
    const float* __restrict__ x,      // [M, K] fp32
    const int* __restrict__ binary,   // [K/32, 4, N]
    const float* __restrict__ alpha,  // [K/128, 4, N]
    const float* __restrict__ q_bias, // [K/128, N]
    __bf16* __restrict__ WT,          // [N, K]
    __bf16* __restrict__ Xb)          // [M, K]
{
    __shared__ __align__(16) unsigned Ls[64 * 132];   // 64 rows x 33 granules

    const int t = threadIdx.x;
    const int bid = blockIdx.x;

    if (bid < 1024) {
        // ---------------- dequant tile ----------------
        const int n0 = (bid & 63) * 64;
        const int k32_0 = (bid >> 6) * 8;
        const int n_l = t & 63;            // lane -> n (coalesced global reads)
        const int k_l = t >> 6;            // wave id 0..3
        const int n = n0 + n_l;

        uint4* L4 = reinterpret_cast<uint4*>(Ls);

#pragma unroll
        for (int c = 0; c < 2; ++c) {
            const int k32 = k32_0 + k_l * 2 + c;
            const int g = k32 >> 2;

            const unsigned w0 = (unsigned)binary[(k32 * 4 + 0) * NDIM + n];
            const unsigned w1 = (unsigned)binary[(k32 * 4 + 1) * NDIM + n];
            const unsigned w2 = (unsigned)binary[(k32 * 4 + 2) * NDIM + n];
            const unsigned w3 = (unsigned)binary[(k32 * 4 + 3) * NDIM + n];
            const float a0 = alpha[(g * 4 + 0) * NDIM + n];
            const float a1 = alpha[(g * 4 + 1) * NDIM + n];
            const float a2 = alpha[(g * 4 + 2) * NDIM + n];
            const float a3 = alpha[(g * 4 + 3) * NDIM + n];
            const float qb = q_bias[g * NDIM + n];

            const int cellg = (k_l * 2 + c) * 4;
#pragma unroll
            for (int j = 0; j < 4; ++j) {                  // granule = 8 weights
                unsigned pk[4];
#pragma unroll
                for (int h = 0; h < 4; ++h) {
                    const int i0 = j * 8 + h * 2;
                    float v0 = qb, v1 = qb;
                    v0 += ((w0 >> i0) & 1u) ? a0 : -a0;
                    v0 += ((w1 >> i0) & 1u) ? a1 : -a1;
                    v0 += ((w2 >> i0) & 1u) ? a2 : -a2;
                    v0 += ((w3 >> i0) & 1u) ? a3 : -a3;
                    const int i1 = i0 + 1;
                    v1 += ((w0 >> i1) & 1u) ? a0 : -a0;
                    v1 += ((w1 >> i1) & 1u) ? a1 : -a1;
                    v1 += ((w2 >> i1) & 1u) ? a2 : -a2;
                    v1 += ((w3 >> i1) & 1u) ? a3 : -a3;
                    const unsigned lo = __builtin_bit_cast(unsigned short, (__bf16)v0);
                    const unsigned hi = __builtin_bit_cast(unsigned short, (__bf16)v1);
                    pk[h] = lo | (hi << 16);
                }
                uint4 q;
                q.x = pk[0]; q.y = pk[1]; q.z = pk[2]; q.w = pk[3];
                L4[n_l * 33 + cellg + j] = q;
            }
        }

        __syncthreads();

        uint4* dstv = reinterpret_cast<uint4*>(WT);
        const int kcol0 = (bid >> 6) * 32;
#pragma unroll
        for (int p = 0; p < 8; ++p) {
            const int idx = p * 256 + t;
            const int row = idx >> 5;
            const int gI = idx & 31;
            const uint4 q = L4[row * 33 + gI];
            dstv[(size_t)(n0 + row) * (KDIM / 8) + kcol0 + gI] = q;
        }
    } else {
        // ---------------- castx ----------------
        const int cb = bid - 1024;         // 0..511
#pragma unroll
        for (int i = 0; i < 8; ++i) {
            const int id = cb * 2048 + i * 256 + t;
            const float4* xv = reinterpret_cast<const float4*>(x) + (size_t)id * 2;
            const float4 v0 = xv[0];
            const float4 v1 = xv[1];
            union { __bf16 h[8]; uint4 q; } u;
            u.h[0] = (__bf16)v0.x; u.h[1] = (__bf16)v0.y;
            u.h[2] = (__bf16)v0.z; u.h[3] = (__bf16)v0.w;
            u.h[4] = (__bf16)v1.x; u.h[5] = (__bf16)v1.y;
            u.h[6] = (__bf16)v1.z; u.h[7] = (__bf16)v1.w;
            reinterpret_cast<uint4*>(Xb)[id] = u.q;
        }
    }
}

// ---------------------------------------------------------------------------
// GEMM: C[M,N] = A[M,K](bf16) * WT[N,K]^T(bf16) + bias, fp32 out.
// (unchanged: 128x128 tile, BK=64, XOR-swizzled global_load_lds)
// ---------------------------------------------------------------------------
__global__ __launch_bounds__(256) void gemm_kernel(
    const __bf16* __restrict__ A,   // [M, K]
    const __bf16* __restrict__ BT,  // [N, K]
    const float* __restrict__ bias, // [N]
    float* __restrict__ C)          // [M, N]
{
    constexpr int BM = 128, BN = 128, BK = 64;
    __shared__ __align__(16) __bf16 As[BM * BK];
    __shared__ __align__(16) __bf16 Bs[BN * BK];

    const int t = threadIdx.x;
    const int lane = t & 63;
    const int wave = t >> 6;
    const int wm = (wave >> 1) << 6;   // 0 or 64
    const int wn = (wave & 1) << 6;
    const int bm = blockIdx.x * BM;
    const int bn = blockIdx.y * BN;

    int a_goff[4], b_goff[4], lds_slot[4];
#pragma unroll
    for (int r = 0; r < 4; ++r) {
        const int s = r * 256 + t;
        const int m = s >> 3;
        const int g = (s & 7) ^ (m & 7);
        lds_slot[r] = s;
        a_goff[r] = (bm + m) * KDIM + g * 8;
        b_goff[r] = (bn + m) * KDIM + g * 8;
    }

    const int r16 = lane & 15;
    const int kq = lane >> 4;
    const int rA = wm + r16;
    const int rB = wn + r16;
    const int aBase = rA * 8, aX = rA & 7;
    const int bBase = rB * 8, bX = rB & 7;

    const bf16x8* Av = reinterpret_cast<const bf16x8*>(As);
    const bf16x8* Bv = reinterpret_cast<const bf16x8*>(Bs);

    f32x4 acc[4][4];
#pragma unroll
    for (int i = 0; i < 4; ++i)
#pragma unroll
        for (int j = 0; j < 4; ++j)
            acc[i][j] = f32x4{0.f, 0.f, 0.f, 0.f};

    for (int kt = 0; kt < KDIM; kt += BK) {
        __syncthreads();
#pragma unroll
        for (int r = 0; r < 4; ++r) {
            load_lds16(A + a_goff[r] + kt, As + lds_slot[r] * 8);
            load_lds16(BT + b_goff[r] + kt, Bs + lds_slot[r] * 8);
        }
        __syncthreads();

#pragma unroll
        for (int ks = 0; ks < 2; ++ks) {
            bf16x8 af[4], bf[4];
#pragma unroll
            for (int mi = 0; mi < 4; ++mi)
                af[mi] = Av[aBase + mi * 128 + ((ks * 4 + kq) ^ aX)];
#pragma unroll
            for (int ni = 0; ni < 4; ++ni)
                bf[ni] = Bv[bBase + ni * 128 + ((ks * 4 + kq) ^ bX)];
#pragma unroll
            for (int mi = 0; mi < 4; ++mi)
#pragma unroll
                for (int ni = 0; ni < 4; ++ni)
                    acc[mi][ni] = __builtin_amdgcn_mfma_f32_16x16x32_bf16(
                        af[mi], bf[ni], acc[mi][ni], 0, 0, 0);
        }
    }

    float bv[4];
#pragma unroll
    for (int ni = 0; ni < 4; ++ni)
        bv[ni] = bias[bn + wn + ni * 16 + r16];

    const int row0 = bm + wm + kq * 4;
#pragma unroll
    for (int mi = 0; mi < 4; ++mi) {
#pragma unroll
        for (int rr = 0; rr < 4; ++rr) {
            const int row = row0 + mi * 16 + rr;
            float* crow = C + (size_t)row * NDIM + bn + wn + r16;
#pragma unroll
            for (int ni = 0; ni < 4; ++ni)
                crow[ni * 16] = acc[mi][ni][rr] + bv[ni];
        }
    }
}

extern "C" void kernel_launch(void* const* d_in, const int* in_sizes, int n_in,
                              void* d_out, int out_size, void* d_ws, size_t ws_size,
                              hipStream_t stream) {
    const float* x      = (const float*)d_in[0];   // [1, 2048, 4096]
    const int*   binary = (const int*)d_in[1];     // [128, 4, 4096]
    const float* alpha  = (const float*)d_in[2];   // [32, 4, 4096]
    const float* q_bias = (const float*)d_in[3];   // [32, 4096]
    const float* bias   = (const float*)d_in[4];   // [4096]
    float* out = (float*)d_out;                    // [1, 2048, 4096] fp32

    __bf16* WT = (__bf16*)d_ws;                        // 32 MB
    __bf16* Xb = WT + (size_t)NDIM * KDIM;             // 16 MB

    prologue_kernel<<<1536, 256, 0, stream>>>(x, binary, alpha, q_bias, WT, Xb);

    dim3 grid(MDIM / 128, NDIM / 128);
    gemm_kernel<<<grid, 256, 0, stream>>>(Xb, WT, bias, out);
}

// Round 6
// 169.735 us; speedup vs baseline: 1.1442x; 1.0604x over previous
//
#include <hip/hip_runtime.h>

#define MDIM 2048
#define NDIM 4096
#define KDIM 4096

typedef __bf16 bf16x8 __attribute__((ext_vector_type(8)));
typedef float f32x4 __attribute__((ext_vector_type(4)));

// CK-style addrspace cast idiom (flat LDS addr low 32 bits == LDS offset on gfx9+)
__device__ inline void load_lds16(const void* gptr, void* lptr) {
    auto g1 = reinterpret_cast<const __attribute__((address_space(1))) unsigned int*>(
        reinterpret_cast<uintptr_t>(gptr));
    auto l3 = reinterpret_cast<__attribute__((address_space(3))) unsigned int*>(
        reinterpret_cast<uintptr_t>(lptr));
    __builtin_amdgcn_global_load_lds(g1, l3, 16, 0, 0);
}

// ---------------------------------------------------------------------------
// Prologue (one dispatch, 1536 blocks) — unchanged from R5 (~at paper cost):
//   blocks 0..1023  : BCQ dequant -> WT bf16 [N,K]  (LDS-transpose tile)
//   blocks 1024..1535: x fp32 -> bf16 Xb [M,K]
// ---------------------------------------------------------------------------
__global__ __launch_bounds__(256) void prologue_kernel(
    const float* __restrict__ x,      // [M, K] fp32
    const int* __restrict__ binary,   // [K/32, 4, N]
    const float* __restrict__ alpha,  // [K/128, 4, N]
    const float* __restrict__ q_bias, // [K/128, N]
    __bf16* __restrict__ WT,          // [N, K]
    __bf16* __restrict__ Xb)          // [M, K]
{
    __shared__ __align__(16) unsigned Ls[64 * 132];   // 64 rows x 33 granules

    const int t = threadIdx.x;
    const int bid = blockIdx.x;

    if (bid < 1024) {
        const int n0 = (bid & 63) * 64;
        const int k32_0 = (bid >> 6) * 8;
        const int n_l = t & 63;            // lane -> n (coalesced global reads)
        const int k_l = t >> 6;            // wave id 0..3
        const int n = n0 + n_l;

        uint4* L4 = reinterpret_cast<uint4*>(Ls);

#pragma unroll
        for (int c = 0; c < 2; ++c) {
            const int k32 = k32_0 + k_l * 2 + c;
            const int g = k32 >> 2;

            const unsigned w0 = (unsigned)binary[(k32 * 4 + 0) * NDIM + n];
            const unsigned w1 = (unsigned)binary[(k32 * 4 + 1) * NDIM + n];
            const unsigned w2 = (unsigned)binary[(k32 * 4 + 2) * NDIM + n];
            const unsigned w3 = (unsigned)binary[(k32 * 4 + 3) * NDIM + n];
            const float a0 = alpha[(g * 4 + 0) * NDIM + n];
            const float a1 = alpha[(g * 4 + 1) * NDIM + n];
            const float a2 = alpha[(g * 4 + 2) * NDIM + n];
            const float a3 = alpha[(g * 4 + 3) * NDIM + n];
            const float qb = q_bias[g * NDIM + n];

            const int cellg = (k_l * 2 + c) * 4;
#pragma unroll
            for (int j = 0; j < 4; ++j) {                  // granule = 8 weights
                unsigned pk[4];
#pragma unroll
                for (int h = 0; h < 4; ++h) {
                    const int i0 = j * 8 + h * 2;
                    float v0 = qb, v1 = qb;
                    v0 += ((w0 >> i0) & 1u) ? a0 : -a0;
                    v0 += ((w1 >> i0) & 1u) ? a1 : -a1;
                    v0 += ((w2 >> i0) & 1u) ? a2 : -a2;
                    v0 += ((w3 >> i0) & 1u) ? a3 : -a3;
                    const int i1 = i0 + 1;
                    v1 += ((w0 >> i1) & 1u) ? a0 : -a0;
                    v1 += ((w1 >> i1) & 1u) ? a1 : -a1;
                    v1 += ((w2 >> i1) & 1u) ? a2 : -a2;
                    v1 += ((w3 >> i1) & 1u) ? a3 : -a3;
                    const unsigned lo = __builtin_bit_cast(unsigned short, (__bf16)v0);
                    const unsigned hi = __builtin_bit_cast(unsigned short, (__bf16)v1);
                    pk[h] = lo | (hi << 16);
                }
                uint4 q;
                q.x = pk[0]; q.y = pk[1]; q.z = pk[2]; q.w = pk[3];
                L4[n_l * 33 + cellg + j] = q;
            }
        }

        __syncthreads();

        uint4* dstv = reinterpret_cast<uint4*>(WT);
        const int kcol0 = (bid >> 6) * 32;
#pragma unroll
        for (int p = 0; p < 8; ++p) {
            const int idx = p * 256 + t;
            const int row = idx >> 5;
            const int gI = idx & 31;
            const uint4 q = L4[row * 33 + gI];
            dstv[(size_t)(n0 + row) * (KDIM / 8) + kcol0 + gI] = q;
        }
    } else {
        const int cb = bid - 1024;         // 0..511
#pragma unroll
        for (int i = 0; i < 8; ++i) {
            const int id = cb * 2048 + i * 256 + t;
            const float4* xv = reinterpret_cast<const float4*>(x) + (size_t)id * 2;
            const float4 v0 = xv[0];
            const float4 v1 = xv[1];
            union { __bf16 h[8]; uint4 q; } u;
            u.h[0] = (__bf16)v0.x; u.h[1] = (__bf16)v0.y;
            u.h[2] = (__bf16)v0.z; u.h[3] = (__bf16)v0.w;
            u.h[4] = (__bf16)v1.x; u.h[5] = (__bf16)v1.y;
            u.h[6] = (__bf16)v1.z; u.h[7] = (__bf16)v1.w;
            reinterpret_cast<uint4*>(Xb)[id] = u.q;
        }
    }
}

// ---------------------------------------------------------------------------
// GEMM v2: explicit double-buffered LDS (64 KB), ONE barrier per K-iter.
// Next tile's global_load_lds issued immediately after the barrier -> a full
// compute phase (~2.5k cyc) hides the ~900-cyc HBM latency; the compiler's
// vmcnt(0)-before-barrier then waits on already-landed loads.
// 128x128 tile, BK=64, XOR granule swizzle (conflict-free, verified R1-R5).
// ---------------------------------------------------------------------------
__global__ __launch_bounds__(256) void gemm_kernel(
    const __bf16* __restrict__ A,   // [M, K]
    const __bf16* __restrict__ BT,  // [N, K]
    const float* __restrict__ bias, // [N]
    float* __restrict__ C)          // [M, N]
{
    constexpr int BM = 128, BN = 128, BK = 64;
    constexpr int NITER = KDIM / BK;
    __shared__ __align__(16) __bf16 As[2][BM * BK];   // 2 x 16 KB
    __shared__ __align__(16) __bf16 Bs[2][BN * BK];   // 2 x 16 KB

    const int t = threadIdx.x;
    const int lane = t & 63;
    const int wave = t >> 6;
    const int wm = (wave >> 1) << 6;   // 0 or 64
    const int wn = (wave & 1) << 6;
    const int bm = blockIdx.x * BM;
    const int bn = blockIdx.y * BN;

    int a_goff[4], b_goff[4], lds_slot[4];
#pragma unroll
    for (int r = 0; r < 4; ++r) {
        const int s = r * 256 + t;
        const int m = s >> 3;
        const int g = (s & 7) ^ (m & 7);
        lds_slot[r] = s;
        a_goff[r] = (bm + m) * KDIM + g * 8;
        b_goff[r] = (bn + m) * KDIM + g * 8;
    }

    const int r16 = lane & 15;
    const int kq = lane >> 4;
    const int rA = wm + r16;
    const int rB = wn + r16;
    const int aBase = rA * 8, aX = rA & 7;
    const int bBase = rB * 8, bX = rB & 7;

    f32x4 acc[4][4];
#pragma unroll
    for (int i = 0; i < 4; ++i)
#pragma unroll
        for (int j = 0; j < 4; ++j)
            acc[i][j] = f32x4{0.f, 0.f, 0.f, 0.f};

    // Stage tile 0 into buffer 0.
#pragma unroll
    for (int r = 0; r < 4; ++r) {
        load_lds16(A + a_goff[r], &As[0][lds_slot[r] * 8]);
        load_lds16(BT + b_goff[r], &Bs[0][lds_slot[r] * 8]);
    }

    for (int it = 0; it < NITER; ++it) {
        const int cur = it & 1;
        // Barrier: drains vmcnt (cur-buffer loads complete) and lgkm (all
        // waves' ds_reads from the nxt buffer's previous contents are done).
        __syncthreads();

        if (it + 1 < NITER) {
            const int kt = (it + 1) * BK;
#pragma unroll
            for (int r = 0; r < 4; ++r) {
                load_lds16(A + a_goff[r] + kt, &As[cur ^ 1][lds_slot[r] * 8]);
                load_lds16(BT + b_goff[r] + kt, &Bs[cur ^ 1][lds_slot[r] * 8]);
            }
        }

        const bf16x8* Av = reinterpret_cast<const bf16x8*>(As[cur]);
        const bf16x8* Bv = reinterpret_cast<const bf16x8*>(Bs[cur]);

#pragma unroll
        for (int ks = 0; ks < 2; ++ks) {
            bf16x8 af[4], bf[4];
#pragma unroll
            for (int mi = 0; mi < 4; ++mi)
                af[mi] = Av[aBase + mi * 128 + ((ks * 4 + kq) ^ aX)];
#pragma unroll
            for (int ni = 0; ni < 4; ++ni)
                bf[ni] = Bv[bBase + ni * 128 + ((ks * 4 + kq) ^ bX)];
#pragma unroll
            for (int mi = 0; mi < 4; ++mi)
#pragma unroll
                for (int ni = 0; ni < 4; ++ni)
                    acc[mi][ni] = __builtin_amdgcn_mfma_f32_16x16x32_bf16(
                        af[mi], bf[ni], acc[mi][ni], 0, 0, 0);
        }
    }

    float bv[4];
#pragma unroll
    for (int ni = 0; ni < 4; ++ni)
        bv[ni] = bias[bn + wn + ni * 16 + r16];

    const int row0 = bm + wm + kq * 4;
#pragma unroll
    for (int mi = 0; mi < 4; ++mi) {
#pragma unroll
        for (int rr = 0; rr < 4; ++rr) {
            const int row = row0 + mi * 16 + rr;
            float* crow = C + (size_t)row * NDIM + bn + wn + r16;
#pragma unroll
            for (int ni = 0; ni < 4; ++ni)
                crow[ni * 16] = acc[mi][ni][rr] + bv[ni];
        }
    }
}

extern "C" void kernel_launch(void* const* d_in, const int* in_sizes, int n_in,
                              void* d_out, int out_size, void* d_ws, size_t ws_size,
                              hipStream_t stream) {
    const float* x      = (const float*)d_in[0];   // [1, 2048, 4096]
    const int*   binary = (const int*)d_in[1];     // [128, 4, 4096]
    const float* alpha  = (const float*)d_in[2];   // [32, 4, 4096]
    const float* q_bias = (const float*)d_in[3];   // [32, 4096]
    const float* bias   = (const float*)d_in[4];   // [4096]
    float* out = (float*)d_out;                    // [1, 2048, 4096] fp32

    __bf16* WT = (__bf16*)d_ws;                        // 32 MB
    __bf16* Xb = WT + (size_t)NDIM * KDIM;             // 16 MB

    prologue_kernel<<<1536, 256, 0, stream>>>(x, binary, alpha, q_bias, WT, Xb);

    dim3 grid(MDIM / 128, NDIM / 128);
    gemm_kernel<<<grid, 256, 0, stream>>>(Xb, WT, bias, out);
}